// Round 1
// baseline (311.806 us; speedup 1.0000x reference)
//
#include <hip/hip_runtime.h>
#include <hip/hip_bf16.h>

// N=100000, K=16, H=128 graph-MLP + global softmax.
// Key identity: sum_k[(r_diff @ w) + b] = [r_sum, K*f - sum_k f[neigh]] @ w + K*b
// -> each stage is one 133-vec x (133x128) matvec per node, not K of them.

#define NN 100000
#define KK 16
#define HH 128

// ---------------- Stage 1: f1 = relu([r_sum, K*p - sum p[nb]] @ w1 + K*b1) ----
__global__ __launch_bounds__(256) void stage1_kernel(
    const float* __restrict__ p, const float* __restrict__ rmat,
    const float* __restrict__ w1, const float* __restrict__ b1,
    const int* __restrict__ idx, float* __restrict__ rsum, float* __restrict__ f1) {
  const int g = threadIdx.x >> 7;   // group 0/1 within block
  const int h = threadIdx.x & 127;
  const int n = blockIdx.x * 2 + g; // grid = NN/2
  __shared__ float s_r[2][80];
  __shared__ float s_pn[2][16];
  __shared__ float s_v[2][8];

  if (h < 80) s_r[g][h] = rmat[n * 80 + h];
  if (h >= 96 && h < 112) {
    int k = h - 96;
    int nb = idx[n * 17 + 1 + k];
    s_pn[g][k] = p[nb];
  }
  __syncthreads();
  if (h < 5) {
    float v = 0.f;
#pragma unroll
    for (int k = 0; k < KK; ++k) v += s_r[g][k * 5 + h];
    s_v[g][h] = v;
    rsum[n * 5 + h] = v;
  } else if (h == 5) {
    float sp = 0.f;
#pragma unroll
    for (int k = 0; k < KK; ++k) sp += s_pn[g][k];
    s_v[g][5] = 16.f * p[n] - sp;
  }
  __syncthreads();
  float acc = 16.f * b1[h];
#pragma unroll
  for (int c = 0; c < 6; ++c) acc += s_v[g][c] * w1[c * HH + h];
  f1[(size_t)n * HH + h] = fmaxf(acc, 0.f);
}

// ---------------- Stage 2: f2 = relu([r_sum, K*f1 - sum f1[nb]] @ w2 + K*b2) --
// w2 (133x128) staged in LDS once per block; 4 groups x 4 nodes per block-iter
// so each LDS w2 read feeds 4 FMAs.
#define S2_ITERS (NN / 16)
__global__ __launch_bounds__(512) void stage2_kernel(
    const float* __restrict__ f1, const float* __restrict__ rsum,
    const float* __restrict__ w2, const float* __restrict__ b2,
    const int* __restrict__ idx, float* __restrict__ f2) {
  __shared__ float s_w2[133 * 128];              // 68096 B
  __shared__ __align__(16) float s_x[16][136];   // 16 nodes x 133 channels (pad)
  __shared__ int s_nb[16][16];
  const int tid = threadIdx.x;
  const int g = tid >> 7;    // 0..3
  const int h = tid & 127;

  for (int i = tid; i < 133 * 128; i += 512) s_w2[i] = w2[i];

  for (int it = blockIdx.x; it < S2_ITERS; it += gridDim.x) {
    const int nbase = it * 16 + g * 4;
    __syncthreads();  // also covers s_w2 on first iter; protects s_x/s_nb reuse
    if (h < 64) {
      int t = h >> 4, k = h & 15;
      s_nb[g * 4 + t][k] = idx[(nbase + t) * 17 + 1 + k];
    } else if (h < 84) {
      int t = (h - 64) / 5, c = (h - 64) % 5;
      s_x[g * 4 + t][c] = rsum[(nbase + t) * 5 + c];
    }
    __syncthreads();
#pragma unroll
    for (int t = 0; t < 4; ++t) {
      const int n = nbase + t;
      float gs = 0.f;
#pragma unroll
      for (int k = 0; k < KK; ++k) gs += f1[(size_t)s_nb[g * 4 + t][k] * HH + h];
      s_x[g * 4 + t][5 + h] = 16.f * f1[(size_t)n * HH + h] - gs;
    }
    __syncthreads();
    float acc0 = 16.f * b2[h];
    float acc1 = acc0, acc2 = acc0, acc3 = acc0;
#pragma unroll
    for (int j = 0; j < 133; ++j) {
      float w = s_w2[j * 128 + h];
      acc0 += s_x[g * 4 + 0][j] * w;
      acc1 += s_x[g * 4 + 1][j] * w;
      acc2 += s_x[g * 4 + 2][j] * w;
      acc3 += s_x[g * 4 + 3][j] * w;
    }
    f2[(size_t)(nbase + 0) * HH + h] = fmaxf(acc0, 0.f);
    f2[(size_t)(nbase + 1) * HH + h] = fmaxf(acc1, 0.f);
    f2[(size_t)(nbase + 2) * HH + h] = fmaxf(acc2, 0.f);
    f2[(size_t)(nbase + 3) * HH + h] = fmaxf(acc3, 0.f);
  }
}

// ---------------- Stage 3: logits[n] = [r_sum, K*f2 - sum f2[nb]] @ w3 + K*b3 -
__global__ __launch_bounds__(256) void stage3_kernel(
    const float* __restrict__ f2, const float* __restrict__ rsum,
    const float* __restrict__ w3, const float* __restrict__ b3,
    const int* __restrict__ idx, float* __restrict__ logits) {
  const int g = threadIdx.x >> 7, h = threadIdx.x & 127;
  const int n = blockIdx.x * 2 + g;
  __shared__ int s_nb[2][16];
  __shared__ float s_red[2][2];
  if (h < 16) s_nb[g][h] = idx[n * 17 + 1 + h];
  __syncthreads();
  float gs = 0.f;
#pragma unroll
  for (int k = 0; k < KK; ++k) gs += f2[(size_t)s_nb[g][k] * HH + h];
  float x = 16.f * f2[(size_t)n * HH + h] - gs;
  float val = x * w3[5 + h];
#pragma unroll
  for (int off = 32; off > 0; off >>= 1) val += __shfl_down(val, off, 64);
  if ((h & 63) == 0) s_red[g][h >> 6] = val;
  __syncthreads();
  if (h == 0) {
    float tot = s_red[g][0] + s_red[g][1];
#pragma unroll
    for (int c = 0; c < 5; ++c) tot += rsum[n * 5 + c] * w3[c];
    tot += 16.f * b3[0];
    logits[n] = tot;
  }
}

// ---------------- Softmax over N ------------------------------------------
__global__ __launch_bounds__(256) void redmax_kernel(const float* __restrict__ lg, float* __restrict__ pmax) {
  __shared__ float s[256];
  int tid = threadIdx.x;
  float m = -3.4e38f;
  for (int i = blockIdx.x * 256 + tid; i < NN; i += 256 * 256) m = fmaxf(m, lg[i]);
  s[tid] = m; __syncthreads();
  for (int off = 128; off > 0; off >>= 1) { if (tid < off) s[tid] = fmaxf(s[tid], s[tid + off]); __syncthreads(); }
  if (tid == 0) pmax[blockIdx.x] = s[0];
}
__global__ __launch_bounds__(256) void finmax_kernel(const float* __restrict__ pmax, float* __restrict__ gmax) {
  __shared__ float s[256];
  int tid = threadIdx.x;
  s[tid] = pmax[tid]; __syncthreads();
  for (int off = 128; off > 0; off >>= 1) { if (tid < off) s[tid] = fmaxf(s[tid], s[tid + off]); __syncthreads(); }
  if (tid == 0) gmax[0] = s[0];
}
__global__ __launch_bounds__(256) void expsum_kernel(const float* __restrict__ lg, const float* __restrict__ gmax,
                                                     float* __restrict__ out, float* __restrict__ psum) {
  __shared__ float s[256];
  int tid = threadIdx.x;
  float m = gmax[0], acc = 0.f;
  for (int i = blockIdx.x * 256 + tid; i < NN; i += 256 * 256) {
    float e = __expf(lg[i] - m);
    out[i] = e;
    acc += e;
  }
  s[tid] = acc; __syncthreads();
  for (int off = 128; off > 0; off >>= 1) { if (tid < off) s[tid] += s[tid + off]; __syncthreads(); }
  if (tid == 0) psum[blockIdx.x] = s[0];
}
__global__ __launch_bounds__(256) void finsum_kernel(const float* __restrict__ psum, float* __restrict__ inv) {
  __shared__ float s[256];
  int tid = threadIdx.x;
  s[tid] = psum[tid]; __syncthreads();
  for (int off = 128; off > 0; off >>= 1) { if (tid < off) s[tid] += s[tid + off]; __syncthreads(); }
  if (tid == 0) inv[0] = 1.f / s[0];
}
__global__ __launch_bounds__(256) void scale_kernel(float* __restrict__ out, const float* __restrict__ inv) {
  int i = blockIdx.x * 256 + threadIdx.x;
  if (i < NN) out[i] *= inv[0];
}

extern "C" void kernel_launch(void* const* d_in, const int* in_sizes, int n_in,
                              void* d_out, int out_size, void* d_ws, size_t ws_size,
                              hipStream_t stream) {
  const float* p    = (const float*)d_in[0];
  const float* rmat = (const float*)d_in[1];
  const float* w1   = (const float*)d_in[2];
  const float* b1   = (const float*)d_in[3];
  const float* w2   = (const float*)d_in[4];
  const float* b2   = (const float*)d_in[5];
  const float* w3   = (const float*)d_in[6];
  const float* b3   = (const float*)d_in[7];
  const int*   idx  = (const int*)d_in[8];
  float* out = (float*)d_out;
  float* ws = (float*)d_ws;

  float* rsum = ws;                        // N*5
  float* f1   = ws + (size_t)NN * 5;       // N*128
  float* f2   = f1 + (size_t)NN * HH;      // N*128
  float* lg   = f2 + (size_t)NN * HH;      // N
  float* pm   = lg + NN;                   // 256
  float* gm   = pm + 256;                  // 1
  float* ps   = gm + 16;                   // 256
  float* inv  = ps + 256;                  // 1

  stage1_kernel<<<NN / 2, 256, 0, stream>>>(p, rmat, w1, b1, idx, rsum, f1);
  stage2_kernel<<<512, 512, 0, stream>>>(f1, rsum, w2, b2, idx, f2);
  stage3_kernel<<<NN / 2, 256, 0, stream>>>(f2, rsum, w3, b3, idx, lg);
  redmax_kernel<<<256, 256, 0, stream>>>(lg, pm);
  finmax_kernel<<<1, 256, 0, stream>>>(pm, gm);
  expsum_kernel<<<256, 256, 0, stream>>>(lg, gm, out, ps);
  finsum_kernel<<<1, 256, 0, stream>>>(ps, inv);
  scale_kernel<<<(NN + 255) / 256, 256, 0, stream>>>(out, inv);
}

// Round 2
// 290.398 us; speedup vs baseline: 1.0737x; 1.0737x over previous
//
#include <hip/hip_runtime.h>
#include <hip/hip_bf16.h>

// N=100000, K=16, H=128 graph-MLP + global softmax.
// Identities used:
//  stage(f)[n] = [r_sum[n], K*f[n] - sum_k f[nb]] @ W + K*b   (sum_k commutes)
//  stage2 split: A = f1@W2h ; D = rsum@W2r + K*b2 + K*A ; f2 = relu(D - sum_k A[nb])
//  stage3 scalarized: s[n] = f2[n].w3h ; logits = K*s[n] - sum_k s[nb] + rsum.w3r + K*b3
//  -> f2 is never materialized; the only big random traffic is the A-gather.

#define NN 100000
#define KK 16
#define HH 128

// ---------------- Stage 1: f1 = relu([r_sum, K*p - sum p[nb]] @ w1 + K*b1) ----
__global__ __launch_bounds__(256) void stage1_kernel(
    const float* __restrict__ p, const float* __restrict__ rmat,
    const float* __restrict__ w1, const float* __restrict__ b1,
    const int* __restrict__ idx, float* __restrict__ rsum, float* __restrict__ f1) {
  const int g = threadIdx.x >> 7;   // group 0/1 within block
  const int h = threadIdx.x & 127;
  const int n = blockIdx.x * 2 + g; // grid = NN/2
  __shared__ float s_r[2][80];
  __shared__ float s_pn[2][16];
  __shared__ float s_v[2][8];

  if (h < 80) s_r[g][h] = rmat[n * 80 + h];
  if (h >= 96 && h < 112) {
    int k = h - 96;
    int nb = idx[n * 17 + 1 + k];
    s_pn[g][k] = p[nb];
  }
  __syncthreads();
  if (h < 5) {
    float v = 0.f;
#pragma unroll
    for (int k = 0; k < KK; ++k) v += s_r[g][k * 5 + h];
    s_v[g][h] = v;
    rsum[n * 5 + h] = v;
  } else if (h == 5) {
    float sp = 0.f;
#pragma unroll
    for (int k = 0; k < KK; ++k) sp += s_pn[g][k];
    s_v[g][5] = 16.f * p[n] - sp;
  }
  __syncthreads();
  float acc = 16.f * b1[h];
#pragma unroll
  for (int c = 0; c < 6; ++c) acc += s_v[g][c] * w1[c * HH + h];
  f1[(size_t)n * HH + h] = fmaxf(acc, 0.f);
}

// ---------------- gemm2: A = f1 @ W2h ; D = rsum @ W2r + 16*b2 + 16*A ---------
// Dense streaming GEMM; W2 staged once per block in LDS.
// NOTE: D aliases f1's storage (rows are read into LDS before being overwritten,
// and tiles are block-exclusive).
#define S2_TILES (NN / 16)
__global__ __launch_bounds__(512) void gemm2_kernel(
    const float* __restrict__ f1, const float* __restrict__ rsum,
    const float* __restrict__ w2, const float* __restrict__ b2,
    float* __restrict__ A, float* __restrict__ D) {
  __shared__ float s_w2[133 * 128];            // 68096 B
  __shared__ float s_f[16][136];               // [node][channel] 0..4 rsum, 5..132 f1
  const int tid = threadIdx.x;
  const int g = tid >> 7;   // 0..3
  const int h = tid & 127;

  for (int i = tid; i < 133 * 128; i += 512) s_w2[i] = w2[i];

  for (int it = blockIdx.x; it < S2_TILES; it += gridDim.x) {
    const int nbase = it * 16;
    __syncthreads();  // protects s_f reuse (and covers s_w2 fill on iter 0)
#pragma unroll
    for (int i = 0; i < 4; ++i) {
      int e = tid + i * 512;            // 2048 elements = 16 rows x 128
      int r = e >> 7, c = e & 127;
      s_f[r][5 + c] = f1[(size_t)(nbase + r) * HH + c];
    }
    if (tid < 80) s_f[tid / 5][tid % 5] = rsum[nbase * 5 + tid];
    __syncthreads();
    const int t0 = g * 4;
    float a0 = 0.f, a1 = 0.f, a2 = 0.f, a3 = 0.f;
#pragma unroll
    for (int j = 5; j < 133; ++j) {
      float w = s_w2[j * 128 + h];
      a0 += s_f[t0 + 0][j] * w;
      a1 += s_f[t0 + 1][j] * w;
      a2 += s_f[t0 + 2][j] * w;
      a3 += s_f[t0 + 3][j] * w;
    }
    float r0 = 16.f * b2[h], r1 = r0, r2 = r0, r3 = r0;
#pragma unroll
    for (int j = 0; j < 5; ++j) {
      float w = s_w2[j * 128 + h];
      r0 += s_f[t0 + 0][j] * w;
      r1 += s_f[t0 + 1][j] * w;
      r2 += s_f[t0 + 2][j] * w;
      r3 += s_f[t0 + 3][j] * w;
    }
    A[(size_t)(nbase + t0 + 0) * HH + h] = a0;
    A[(size_t)(nbase + t0 + 1) * HH + h] = a1;
    A[(size_t)(nbase + t0 + 2) * HH + h] = a2;
    A[(size_t)(nbase + t0 + 3) * HH + h] = a3;
    D[(size_t)(nbase + t0 + 0) * HH + h] = r0 + 16.f * a0;
    D[(size_t)(nbase + t0 + 1) * HH + h] = r1 + 16.f * a1;
    D[(size_t)(nbase + t0 + 2) * HH + h] = r2 + 16.f * a2;
    D[(size_t)(nbase + t0 + 3) * HH + h] = r3 + 16.f * a3;
  }
}

// ---------------- gather2: s[n] = relu(D[n] - sum_k A[nb]) . w3h ---------------
// One wave per node, no LDS, no __syncthreads -> full occupancy, max MLP.
__global__ __launch_bounds__(256) void gather2_kernel(
    const float* __restrict__ A, const float* __restrict__ D,
    const float* __restrict__ w3, const int* __restrict__ idx,
    float* __restrict__ sv) {
  const int lane = threadIdx.x & 63;
  const int wid = (blockIdx.x << 2) + (threadIdx.x >> 6);
  const float w3a = w3[5 + lane];
  const float w3b = w3[69 + lane];
  const int nwaves = gridDim.x << 2;
  for (int n = wid; n < NN; n += nwaves) {
    const int* nb = idx + (size_t)n * 17 + 1;
    const float* Dn = D + (size_t)n * HH;
    float acc0 = Dn[lane];
    float acc1 = Dn[64 + lane];
#pragma unroll
    for (int k = 0; k < KK; ++k) {
      const float* Ar = A + (size_t)nb[k] * HH;
      acc0 -= Ar[lane];
      acc1 -= Ar[64 + lane];
    }
    float v = fmaxf(acc0, 0.f) * w3a + fmaxf(acc1, 0.f) * w3b;
#pragma unroll
    for (int off = 32; off > 0; off >>= 1) v += __shfl_down(v, off, 64);
    if (lane == 0) sv[n] = v;
  }
}

// ---------------- stage3: logits[n] = 16*s[n] - sum_k s[nb] + rsum.w3r + 16*b3 -
__global__ __launch_bounds__(256) void stage3s_kernel(
    const float* __restrict__ sv, const float* __restrict__ rsum,
    const float* __restrict__ w3, const float* __restrict__ b3,
    const int* __restrict__ idx, float* __restrict__ lg) {
  const int n = blockIdx.x * 256 + threadIdx.x;
  if (n >= NN) return;
  float t = 16.f * sv[n];
  const int* nb = idx + (size_t)n * 17 + 1;
#pragma unroll
  for (int k = 0; k < KK; ++k) t -= sv[nb[k]];
#pragma unroll
  for (int c = 0; c < 5; ++c) t += rsum[n * 5 + c] * w3[c];
  lg[n] = t + 16.f * b3[0];
}

// ---------------- Softmax over N ------------------------------------------
__global__ __launch_bounds__(256) void redmax_kernel(const float* __restrict__ lg, float* __restrict__ pmax) {
  __shared__ float s[256];
  int tid = threadIdx.x;
  float m = -3.4e38f;
  for (int i = blockIdx.x * 256 + tid; i < NN; i += 256 * 256) m = fmaxf(m, lg[i]);
  s[tid] = m; __syncthreads();
  for (int off = 128; off > 0; off >>= 1) { if (tid < off) s[tid] = fmaxf(s[tid], s[tid + off]); __syncthreads(); }
  if (tid == 0) pmax[blockIdx.x] = s[0];
}
__global__ __launch_bounds__(256) void finmax_kernel(const float* __restrict__ pmax, float* __restrict__ gmax) {
  __shared__ float s[256];
  int tid = threadIdx.x;
  s[tid] = pmax[tid]; __syncthreads();
  for (int off = 128; off > 0; off >>= 1) { if (tid < off) s[tid] = fmaxf(s[tid], s[tid + off]); __syncthreads(); }
  if (tid == 0) gmax[0] = s[0];
}
__global__ __launch_bounds__(256) void expsum_kernel(const float* __restrict__ lg, const float* __restrict__ gmax,
                                                     float* __restrict__ out, float* __restrict__ psum) {
  __shared__ float s[256];
  int tid = threadIdx.x;
  float m = gmax[0], acc = 0.f;
  for (int i = blockIdx.x * 256 + tid; i < NN; i += 256 * 256) {
    float e = __expf(lg[i] - m);
    out[i] = e;
    acc += e;
  }
  s[tid] = acc; __syncthreads();
  for (int off = 128; off > 0; off >>= 1) { if (tid < off) s[tid] += s[tid + off]; __syncthreads(); }
  if (tid == 0) psum[blockIdx.x] = s[0];
}
__global__ __launch_bounds__(256) void finsum_kernel(const float* __restrict__ psum, float* __restrict__ inv) {
  __shared__ float s[256];
  int tid = threadIdx.x;
  s[tid] = psum[tid]; __syncthreads();
  for (int off = 128; off > 0; off >>= 1) { if (tid < off) s[tid] += s[tid + off]; __syncthreads(); }
  if (tid == 0) inv[0] = 1.f / s[0];
}
__global__ __launch_bounds__(256) void scale_kernel(float* __restrict__ out, const float* __restrict__ inv) {
  int i = blockIdx.x * 256 + threadIdx.x;
  if (i < NN) out[i] *= inv[0];
}

extern "C" void kernel_launch(void* const* d_in, const int* in_sizes, int n_in,
                              void* d_out, int out_size, void* d_ws, size_t ws_size,
                              hipStream_t stream) {
  const float* p    = (const float*)d_in[0];
  const float* rmat = (const float*)d_in[1];
  const float* w1   = (const float*)d_in[2];
  const float* b1   = (const float*)d_in[3];
  const float* w2   = (const float*)d_in[4];
  const float* b2   = (const float*)d_in[5];
  const float* w3   = (const float*)d_in[6];
  const float* b3   = (const float*)d_in[7];
  const int*   idx  = (const int*)d_in[8];
  float* out = (float*)d_out;
  float* ws = (float*)d_ws;

  float* rsum = ws;                        // N*5
  float* f1   = ws + (size_t)NN * 5;       // N*128 (later reused as D)
  float* A    = f1 + (size_t)NN * HH;      // N*128
  float* D    = f1;                        // alias: gemm2 reads f1 rows before writing D
  float* sv   = A + (size_t)NN * HH;       // N
  float* lg   = sv + NN;                   // N
  float* pm   = lg + NN;                   // 256
  float* gm   = pm + 256;                  // 16
  float* ps   = gm + 16;                   // 256
  float* inv  = ps + 256;                  // 1

  stage1_kernel<<<NN / 2, 256, 0, stream>>>(p, rmat, w1, b1, idx, rsum, f1);
  gemm2_kernel<<<512, 512, 0, stream>>>(f1, rsum, w2, b2, A, D);
  gather2_kernel<<<2048, 256, 0, stream>>>(A, D, w3, idx, sv);
  stage3s_kernel<<<(NN + 255) / 256, 256, 0, stream>>>(sv, rsum, w3, b3, idx, lg);
  redmax_kernel<<<256, 256, 0, stream>>>(lg, pm);
  finmax_kernel<<<1, 256, 0, stream>>>(pm, gm);
  expsum_kernel<<<256, 256, 0, stream>>>(lg, gm, out, ps);
  finsum_kernel<<<1, 256, 0, stream>>>(ps, inv);
  scale_kernel<<<(NN + 255) / 256, 256, 0, stream>>>(out, inv);
}